// Round 1
// 398.891 us; speedup vs baseline: 1.0525x; 1.0525x over previous
//
#include <hip/hip_runtime.h>
#include <math.h>

// Metric/discriminative instance loss. B=4, D=64, H=W=512, K=32.
// Sufficient stats as one-hot GEMM via MFMA:
//   sums[k][d] = onehot[k][pix] @ f[pix][d]
//   ssq[k]     = onehot @ f^2  (then sum over d)
//   cnt[k]     = onehot @ 1
// var identity: segsum(||f-mu||^2)[k] = ssq[k] - cnt[k]*||mu_k||^2.
//
// R(this): atomic-free 3-kernel pipeline. Previous version accumulated
// per-block stats with 4.3M device-scope atomicAdds (512-way same-address
// contention per image). Now: per-block partials (plain coalesced stores,
// 17.3 MB) -> tree reduce (576 blocks) -> 4-block parallel finalize.
// No hipMemsetAsync needed (every ws cell written before read).
// Workspace use: B*GPB*2112*4 + B*ZSPLIT*2112*4 ~= 17.9 MB.
// Memory floor ~43 us (260 MB @ 6.3 TB/s) + ~6 us partial round-trip.

#define KSEG 32
#define DF   64
#define STATS_STRIDE 2112   // 32*64 sums + 32 cnt + 32 ssq
#define GPB  512            // blocks per image; 512 pixels/block = 16 chunks
#define ZSPLIT 16           // reduce split: 16 z-blocks of 32 partials each
#define GPZ  (GPB / ZSPLIT) // 32

typedef _Float16 half8 __attribute__((ext_vector_type(8)));
typedef float f32x4 __attribute__((ext_vector_type(4)));

// ---------------- Pass 1: MFMA one-hot stats -> per-block partial ----------------
// Block: 256 thr = 4 waves. Wave w owns d in [16w, 16w+16). Lane l: m=l&15
// (cluster row for A / d-col for B), q=l>>4 (8-pixel group within 32-chunk).
__global__ __launch_bounds__(256) void stats_kernel(
    const float* __restrict__ feats, const int* __restrict__ labels,
    float* __restrict__ partial, int N) {
  const int b = blockIdx.y, g = blockIdx.x;
  const int tid = threadIdx.x;
  const int w = tid >> 6, lane = tid & 63;
  const int m = lane & 15, q = lane >> 4;

  const float* __restrict__ fimg = feats + (size_t)b * DF * N;
  const int* __restrict__ limg = labels + (size_t)b * N;
  const int pix0 = g * (N / GPB);          // 512 pixels per block
  const int d = 16 * w + m;
  const float* __restrict__ frow = fimg + (size_t)d * N;

  f32x4 c_sum0 = {0.f, 0.f, 0.f, 0.f}, c_sum1 = {0.f, 0.f, 0.f, 0.f};
  f32x4 c_sq0 = {0.f, 0.f, 0.f, 0.f}, c_sq1 = {0.f, 0.f, 0.f, 0.f};
  f32x4 c_cn0 = {0.f, 0.f, 0.f, 0.f}, c_cn1 = {0.f, 0.f, 0.f, 0.f};
  const _Float16 h1 = (_Float16)1.0f, h0 = (_Float16)0.0f;
  half8 ones = {h1, h1, h1, h1, h1, h1, h1, h1};

#pragma unroll 4
  for (int c = 0; c < 16; ++c) {           // 16 chunks of 32 pixels
    const int pb = pix0 + c * 32 + q * 8;  // lane's 8 consecutive pixels
    const float4 fA = *(const float4*)(frow + pb);
    const float4 fB = *(const float4*)(frow + pb + 4);
    const int4 lA = *(const int4*)(limg + pb);
    const int4 lB = *(const int4*)(limg + pb + 4);

    float fv[8] = {fA.x, fA.y, fA.z, fA.w, fB.x, fB.y, fB.z, fB.w};
    int lv[8] = {lA.x, lA.y, lA.z, lA.w, lB.x, lB.y, lB.z, lB.w};

    half8 bf, bsq, a0, a1;
#pragma unroll
    for (int j = 0; j < 8; ++j) {
      const _Float16 h = (_Float16)fv[j];  // v_cvt_f16_f32, RNE (unbiased)
      bf[j] = h;
      bsq[j] = h * h;
      a0[j] = (lv[j] == m) ? h1 : h0;
      a1[j] = (lv[j] == m + 16) ? h1 : h0;
    }
    c_sum0 = __builtin_amdgcn_mfma_f32_16x16x32_f16(a0, bf, c_sum0, 0, 0, 0);
    c_sum1 = __builtin_amdgcn_mfma_f32_16x16x32_f16(a1, bf, c_sum1, 0, 0, 0);
    c_sq0 = __builtin_amdgcn_mfma_f32_16x16x32_f16(a0, bsq, c_sq0, 0, 0, 0);
    c_sq1 = __builtin_amdgcn_mfma_f32_16x16x32_f16(a1, bsq, c_sq1, 0, 0, 0);
    c_cn0 = __builtin_amdgcn_mfma_f32_16x16x32_f16(a0, ones, c_cn0, 0, 0, 0);
    c_cn1 = __builtin_amdgcn_mfma_f32_16x16x32_f16(a1, ones, c_cn1, 0, 0, 0);
  }

  // Block-level assembly in LDS (each cell written exactly once), then
  // plain coalesced stores to this block's private partial slice.
  __shared__ float lsum[KSEG][DF + 1];
  __shared__ float lssq[KSEG][DF + 1];
  __shared__ float lcnt[KSEG];
#pragma unroll
  for (int r = 0; r < 4; ++r) {
    const int k0 = q * 4 + r;              // C/D: row=(lane>>4)*4+reg
    lsum[k0][16 * w + m] = c_sum0[r];
    lsum[k0 + 16][16 * w + m] = c_sum1[r];
    lssq[k0][16 * w + m] = c_sq0[r];
    lssq[k0 + 16][16 * w + m] = c_sq1[r];
  }
  if (w == 0 && m == 0) {                  // cnt: all d-cols identical; take col 0
#pragma unroll
    for (int r = 0; r < 4; ++r) {
      lcnt[q * 4 + r] = c_cn0[r];
      lcnt[16 + q * 4 + r] = c_cn1[r];
    }
  }
  __syncthreads();

  float* so = partial + (size_t)(b * GPB + g) * STATS_STRIDE;
  for (int i = tid; i < KSEG * DF; i += 256)
    so[i] = lsum[i >> 6][i & 63];
  if (tid < KSEG) {
    float s = 0.f;
    for (int dd = 0; dd < DF; ++dd) s += lssq[tid][dd];  // conflict-free: (tid+dd)%32
    so[KSEG * DF + tid] = lcnt[tid];
    so[KSEG * DF + KSEG + tid] = s;
  }
}

// ---------------- Pass 2: tree reduce partials (no atomics) ----------------
// Grid (9, B, ZSPLIT). Block (x,b,z): idx = x*256+tid, sums 32 consecutive
// g-partials (coalesced 256B per wave-instr, stride 8448B between iters).
__global__ __launch_bounds__(256) void reduce_kernel(
    const float* __restrict__ partial, float* __restrict__ p2,
    float* __restrict__ out) {
  if (blockIdx.x == 0 && blockIdx.y == 0 && blockIdx.z == 0 && threadIdx.x == 0)
    out[0] = 0.f;                          // finalize atomicAdds into this
  const int idx = blockIdx.x * 256 + threadIdx.x;
  if (idx >= STATS_STRIDE) return;
  const int b = blockIdx.y, z = blockIdx.z;
  const float* __restrict__ src =
      partial + (size_t)(b * GPB + z * GPZ) * STATS_STRIDE + idx;
  float s = 0.f;
#pragma unroll 8
  for (int g = 0; g < GPZ; ++g) s += src[(size_t)g * STATS_STRIDE];
  p2[(size_t)(b * ZSPLIT + z) * STATS_STRIDE + idx] = s;
}

// ---------------- Pass 3: finalize, one block per image ----------------
__global__ __launch_bounds__(256) void finalize_kernel(
    const float* __restrict__ p2, float* __restrict__ out) {
  __shared__ float mu[KSEG][DF + 1];
  __shared__ float cntS[KSEG], ssqS[KSEG], musqS[KSEG];
  __shared__ float wred[4];
  const int tid = threadIdx.x;
  const int b = blockIdx.x;
  const float* __restrict__ base = p2 + (size_t)b * ZSPLIT * STATS_STRIDE;

  if (tid < KSEG) {
    float c = 0.f, s = 0.f;
    for (int z = 0; z < ZSPLIT; ++z) {
      c += base[(size_t)z * STATS_STRIDE + KSEG * DF + tid];
      s += base[(size_t)z * STATS_STRIDE + KSEG * DF + KSEG + tid];
    }
    cntS[tid] = c;
    ssqS[tid] = s;
  }
  __syncthreads();
  for (int idx = tid; idx < KSEG * DF; idx += 256) {
    float s = 0.f;
    for (int z = 0; z < ZSPLIT; ++z) s += base[(size_t)z * STATS_STRIDE + idx];
    mu[idx >> 6][idx & 63] = s / fmaxf(cntS[idx >> 6], 1.f);
  }
  __syncthreads();
  if (tid < KSEG) {
    float m2 = 0.f;
    for (int dd = 0; dd < DF; ++dd) m2 = fmaf(mu[tid][dd], mu[tid][dd], m2);
    musqS[tid] = m2;
  }
  __syncthreads();

  float hacc = 0.f;
  for (int p = tid; p < KSEG * KSEG; p += 256) {
    const int i = p >> 5, j = p & 31;
    if (i < j && cntS[i] > 0.f && cntS[j] > 0.f) {
      float dsq = 0.f;
      for (int dd = 0; dd < DF; ++dd) {
        const float df = mu[i][dd] - mu[j][dd];
        dsq = fmaf(df, df, dsq);
      }
      const float h = 2.f * 1.5f - sqrtf(dsq);  // 2*DD - dist
      if (h > 0.f) hacc += h * h;
    }
  }
  for (int off = 32; off > 0; off >>= 1) hacc += __shfl_down(hacc, off, 64);
  if ((tid & 63) == 0) wred[tid >> 6] = hacc;
  __syncthreads();

  if (tid == 0) {
    const float dsum = wred[0] + wred[1] + wred[2] + wred[3];
    float var = 0.f, reg = 0.f, ncl = 0.f;
    for (int k = 0; k < KSEG; ++k) {
      const float c = cntS[k];
      if (c > 0.f) {
        ncl += 1.f;
        var += ssqS[k] / c - musqS[k];
        reg += sqrtf(musqS[k]);
      }
    }
    const float dist_loss = dsum / fmaxf(ncl - 1.f, 1.f);
    const float loss = (var + dist_loss + 0.001f * reg) / ncl;
    atomicAdd(out, loss / (float)(gridDim.x + 1));  // /(B+1)
  }
}

extern "C" void kernel_launch(void* const* d_in, const int* in_sizes, int n_in,
                              void* d_out, int out_size, void* d_ws, size_t ws_size,
                              hipStream_t stream) {
  const float* feats = (const float*)d_in[0];
  const int* labels = (const int*)d_in[1];
  float* out = (float*)d_out;

  const int B = 4;
  const int BHW = in_sizes[1];
  const int N = BHW / B;  // 262144

  float* partial = (float*)d_ws;                            // B*GPB*2112 floats
  float* p2 = partial + (size_t)B * GPB * STATS_STRIDE;     // B*ZSPLIT*2112 floats

  stats_kernel<<<dim3(GPB, B), 256, 0, stream>>>(feats, labels, partial, N);
  reduce_kernel<<<dim3((STATS_STRIDE + 255) / 256, B, ZSPLIT), 256, 0, stream>>>(
      partial, p2, out);
  finalize_kernel<<<dim3(B), 256, 0, stream>>>(p2, out);
}

// Round 3
// 385.914 us; speedup vs baseline: 1.0879x; 1.0336x over previous
//
#include <hip/hip_runtime.h>
#include <math.h>

// Metric/discriminative instance loss. B=4, D=64, H=W=512, K=32.
// Sufficient stats as one-hot GEMM via MFMA:
//   sums[k][d] = onehot[k][pix] @ f[pix][d]
//   ssq[k]     = onehot @ f^2  (then sum over d)
//   cnt[k]     = onehot @ 1
// var identity: segsum(||f-mu||^2)[k] = ssq[k] - cnt[k]*||mu_k||^2.
//
// R3 (= R2 intent, compile-fixed): nontemporal builtin needs ext_vector_type,
// not HIP_vector_type<float,4>. GPB 512->256 (halves partial round-trip to
// 2x8.6MB), nontemporal feats loads (single-use stream; keep L2 for labels).
// ~320 us of measured time is harness workspace poison-fill (2x 1.07GB
// fillBufferAligned @ 83% HBM peak, in timed window, not controllable).
// Memory floor ~43 us (260 MB @ 6.3 TB/s) + ~3 us partial round-trip.

#define KSEG 32
#define DF   64
#define STATS_STRIDE 2112   // 32*64 sums + 32 cnt + 32 ssq
#define GPB  256            // blocks per image; 1024 pixels/block = 32 chunks
#define CHUNKS 32
#define ZSPLIT 8            // reduce split: 8 z-blocks of 32 partials each
#define GPZ  (GPB / ZSPLIT) // 32

typedef _Float16 half8 __attribute__((ext_vector_type(8)));
typedef float f32x4 __attribute__((ext_vector_type(4)));
typedef float fvec4 __attribute__((ext_vector_type(4)));   // for nontemporal loads
typedef int ivec4 __attribute__((ext_vector_type(4)));

// ---------------- Pass 1: MFMA one-hot stats -> per-block partial ----------------
// Block: 256 thr = 4 waves. Wave w owns d in [16w, 16w+16). Lane l: m=l&15
// (cluster row for A / d-col for B), q=l>>4 (8-pixel group within 32-chunk).
__global__ __launch_bounds__(256) void stats_kernel(
    const float* __restrict__ feats, const int* __restrict__ labels,
    float* __restrict__ partial, int N) {
  const int b = blockIdx.y, g = blockIdx.x;
  const int tid = threadIdx.x;
  const int w = tid >> 6, lane = tid & 63;
  const int m = lane & 15, q = lane >> 4;

  const float* __restrict__ fimg = feats + (size_t)b * DF * N;
  const int* __restrict__ limg = labels + (size_t)b * N;
  const int pix0 = g * (N / GPB);          // 1024 pixels per block
  const int d = 16 * w + m;
  const float* __restrict__ frow = fimg + (size_t)d * N;

  f32x4 c_sum0 = {0.f, 0.f, 0.f, 0.f}, c_sum1 = {0.f, 0.f, 0.f, 0.f};
  f32x4 c_sq0 = {0.f, 0.f, 0.f, 0.f}, c_sq1 = {0.f, 0.f, 0.f, 0.f};
  f32x4 c_cn0 = {0.f, 0.f, 0.f, 0.f}, c_cn1 = {0.f, 0.f, 0.f, 0.f};
  const _Float16 h1 = (_Float16)1.0f, h0 = (_Float16)0.0f;
  half8 ones = {h1, h1, h1, h1, h1, h1, h1, h1};

#pragma unroll 4
  for (int c = 0; c < CHUNKS; ++c) {       // chunks of 32 pixels
    const int pb = pix0 + c * 32 + q * 8;  // lane's 8 consecutive pixels
    const fvec4 fA = __builtin_nontemporal_load((const fvec4*)(frow + pb));
    const fvec4 fB = __builtin_nontemporal_load((const fvec4*)(frow + pb + 4));
    const ivec4 lA = *(const ivec4*)(limg + pb);   // labels reused 4x/block: cache
    const ivec4 lB = *(const ivec4*)(limg + pb + 4);

    float fv[8] = {fA[0], fA[1], fA[2], fA[3], fB[0], fB[1], fB[2], fB[3]};
    int lv[8] = {lA[0], lA[1], lA[2], lA[3], lB[0], lB[1], lB[2], lB[3]};

    half8 bf, bsq, a0, a1;
#pragma unroll
    for (int j = 0; j < 8; ++j) {
      const _Float16 h = (_Float16)fv[j];  // v_cvt_f16_f32, RNE (unbiased)
      bf[j] = h;
      bsq[j] = h * h;
      a0[j] = (lv[j] == m) ? h1 : h0;
      a1[j] = (lv[j] == m + 16) ? h1 : h0;
    }
    c_sum0 = __builtin_amdgcn_mfma_f32_16x16x32_f16(a0, bf, c_sum0, 0, 0, 0);
    c_sum1 = __builtin_amdgcn_mfma_f32_16x16x32_f16(a1, bf, c_sum1, 0, 0, 0);
    c_sq0 = __builtin_amdgcn_mfma_f32_16x16x32_f16(a0, bsq, c_sq0, 0, 0, 0);
    c_sq1 = __builtin_amdgcn_mfma_f32_16x16x32_f16(a1, bsq, c_sq1, 0, 0, 0);
    c_cn0 = __builtin_amdgcn_mfma_f32_16x16x32_f16(a0, ones, c_cn0, 0, 0, 0);
    c_cn1 = __builtin_amdgcn_mfma_f32_16x16x32_f16(a1, ones, c_cn1, 0, 0, 0);
  }

  // Block-level assembly in LDS (each cell written exactly once), then
  // plain coalesced stores to this block's private partial slice.
  __shared__ float lsum[KSEG][DF + 1];
  __shared__ float lssq[KSEG][DF + 1];
  __shared__ float lcnt[KSEG];
#pragma unroll
  for (int r = 0; r < 4; ++r) {
    const int k0 = q * 4 + r;              // C/D: row=(lane>>4)*4+reg
    lsum[k0][16 * w + m] = c_sum0[r];
    lsum[k0 + 16][16 * w + m] = c_sum1[r];
    lssq[k0][16 * w + m] = c_sq0[r];
    lssq[k0 + 16][16 * w + m] = c_sq1[r];
  }
  if (w == 0 && m == 0) {                  // cnt: all d-cols identical; take col 0
#pragma unroll
    for (int r = 0; r < 4; ++r) {
      lcnt[q * 4 + r] = c_cn0[r];
      lcnt[16 + q * 4 + r] = c_cn1[r];
    }
  }
  __syncthreads();

  float* so = partial + (size_t)(b * GPB + g) * STATS_STRIDE;
  for (int i = tid; i < KSEG * DF; i += 256)
    so[i] = lsum[i >> 6][i & 63];
  if (tid < KSEG) {
    float s = 0.f;
    for (int dd = 0; dd < DF; ++dd) s += lssq[tid][dd];  // conflict-free: (tid+dd)%32
    so[KSEG * DF + tid] = lcnt[tid];
    so[KSEG * DF + KSEG + tid] = s;
  }
}

// ---------------- Pass 2: tree reduce partials (no atomics) ----------------
// Grid (9, B, ZSPLIT). Block (x,b,z): idx = x*256+tid, sums 32 consecutive
// g-partials (coalesced 1KB per wave-instr, stride 8448B between iters).
__global__ __launch_bounds__(256) void reduce_kernel(
    const float* __restrict__ partial, float* __restrict__ p2,
    float* __restrict__ out) {
  if (blockIdx.x == 0 && blockIdx.y == 0 && blockIdx.z == 0 && threadIdx.x == 0)
    out[0] = 0.f;                          // finalize atomicAdds into this
  const int idx = blockIdx.x * 256 + threadIdx.x;
  if (idx >= STATS_STRIDE) return;
  const int b = blockIdx.y, z = blockIdx.z;
  const float* __restrict__ src =
      partial + (size_t)(b * GPB + z * GPZ) * STATS_STRIDE + idx;
  float s = 0.f;
#pragma unroll 8
  for (int g = 0; g < GPZ; ++g) s += src[(size_t)g * STATS_STRIDE];
  p2[(size_t)(b * ZSPLIT + z) * STATS_STRIDE + idx] = s;
}

// ---------------- Pass 3: finalize, one block per image ----------------
__global__ __launch_bounds__(256) void finalize_kernel(
    const float* __restrict__ p2, float* __restrict__ out) {
  __shared__ float mu[KSEG][DF + 1];
  __shared__ float cntS[KSEG], ssqS[KSEG], musqS[KSEG];
  __shared__ float wred[4];
  const int tid = threadIdx.x;
  const int b = blockIdx.x;
  const float* __restrict__ base = p2 + (size_t)b * ZSPLIT * STATS_STRIDE;

  if (tid < KSEG) {
    float c = 0.f, s = 0.f;
    for (int z = 0; z < ZSPLIT; ++z) {
      c += base[(size_t)z * STATS_STRIDE + KSEG * DF + tid];
      s += base[(size_t)z * STATS_STRIDE + KSEG * DF + KSEG + tid];
    }
    cntS[tid] = c;
    ssqS[tid] = s;
  }
  __syncthreads();
  for (int idx = tid; idx < KSEG * DF; idx += 256) {
    float s = 0.f;
    for (int z = 0; z < ZSPLIT; ++z) s += base[(size_t)z * STATS_STRIDE + idx];
    mu[idx >> 6][idx & 63] = s / fmaxf(cntS[idx >> 6], 1.f);
  }
  __syncthreads();
  if (tid < KSEG) {
    float m2 = 0.f;
    for (int dd = 0; dd < DF; ++dd) m2 = fmaf(mu[tid][dd], mu[tid][dd], m2);
    musqS[tid] = m2;
  }
  __syncthreads();

  float hacc = 0.f;
  for (int p = tid; p < KSEG * KSEG; p += 256) {
    const int i = p >> 5, j = p & 31;
    if (i < j && cntS[i] > 0.f && cntS[j] > 0.f) {
      float dsq = 0.f;
      for (int dd = 0; dd < DF; ++dd) {
        const float df = mu[i][dd] - mu[j][dd];
        dsq = fmaf(df, df, dsq);
      }
      const float h = 2.f * 1.5f - sqrtf(dsq);  // 2*DD - dist
      if (h > 0.f) hacc += h * h;
    }
  }
  for (int off = 32; off > 0; off >>= 1) hacc += __shfl_down(hacc, off, 64);
  if ((tid & 63) == 0) wred[tid >> 6] = hacc;
  __syncthreads();

  if (tid == 0) {
    const float dsum = wred[0] + wred[1] + wred[2] + wred[3];
    float var = 0.f, reg = 0.f, ncl = 0.f;
    for (int k = 0; k < KSEG; ++k) {
      const float c = cntS[k];
      if (c > 0.f) {
        ncl += 1.f;
        var += ssqS[k] / c - musqS[k];
        reg += sqrtf(musqS[k]);
      }
    }
    const float dist_loss = dsum / fmaxf(ncl - 1.f, 1.f);
    const float loss = (var + dist_loss + 0.001f * reg) / ncl;
    atomicAdd(out, loss / (float)(gridDim.x + 1));  // /(B+1)
  }
}

extern "C" void kernel_launch(void* const* d_in, const int* in_sizes, int n_in,
                              void* d_out, int out_size, void* d_ws, size_t ws_size,
                              hipStream_t stream) {
  const float* feats = (const float*)d_in[0];
  const int* labels = (const int*)d_in[1];
  float* out = (float*)d_out;

  const int B = 4;
  const int BHW = in_sizes[1];
  const int N = BHW / B;  // 262144

  float* partial = (float*)d_ws;                            // B*GPB*2112 floats
  float* p2 = partial + (size_t)B * GPB * STATS_STRIDE;     // B*ZSPLIT*2112 floats

  stats_kernel<<<dim3(GPB, B), 256, 0, stream>>>(feats, labels, partial, N);
  reduce_kernel<<<dim3((STATS_STRIDE + 255) / 256, B, ZSPLIT), 256, 0, stream>>>(
      partial, p2, out);
  finalize_kernel<<<dim3(B), 256, 0, stream>>>(p2, out);
}